// Round 6
// baseline (273.833 us; speedup 1.0000x reference)
//
#include <hip/hip_runtime.h>

#define BD 256

// ---- ws offsets (floats), total 102928 floats = 412 KB ----
#define WS_PQ   0         // [48][256]  (prims@Wq)/16   (pre1 -> pre2)
#define WS_MF   12288     // 65536 halfs: M  bf16 B-fragments
#define WS_WZF  45056     // 65536 halfs: Wz bf16 B-fragments
#define WS_OB   77824     // [256]      m*(bv@out_w^T + out_b)
#define WS_BQK  78080     // [4][64]    bq-side constants /8
#define WS_LW   78336     // [16]       softmax(level_weights)
#define WS_KP   78352     // [48][256]  prims@Wk^T (pre1 -> pre2)
#define WS_VP   90640     // [48][256]  prims@Wv^T (pre1 -> pre2)
#define WS_TOTAL 102928

typedef __bf16 bf16x8 __attribute__((ext_vector_type(8)));
typedef float  f32x4  __attribute__((ext_vector_type(4)));

__device__ __forceinline__ float bf2f(unsigned short u) {
  union { float f; unsigned int i; } c; c.i = ((unsigned int)u) << 16; return c.f;
}
__device__ __forceinline__ unsigned short f2bf(float f) {
  union { float f; unsigned int i; } c; c.f = f;
  unsigned int x = c.i;
  unsigned int r = (x + 0x7fffu + ((x >> 16) & 1u)) >> 16;
  return (unsigned short)r;
}
// B-fragment half-index for X[k][col] (16x16x32 bf16 B operand):
// e = ((kt*16+ct)*64 + lane)*8 + i, k = kt*32+(lane>>4)*8+i, col = ct*16+(lane&15)
__device__ __forceinline__ int frag_idx(int k, int col) {
  return (((k >> 5) * 16 + (col >> 4)) * 64 + (((k >> 3) & 3) * 16 + (col & 15))) * 8 + (k & 7);
}

// ---------------- pre1: Kp, Vp, PQ, OB, LW (unchanged from r5, proven) ----------------
__global__ void hpm_pre1(const float* __restrict__ prims, const float* __restrict__ lvlw,
                         const float* __restrict__ wq, const float* __restrict__ ipw,
                         const float* __restrict__ ipb, const float* __restrict__ outw,
                         const float* __restrict__ outb, const float* __restrict__ caw,
                         float* __restrict__ ws) {
  int t = threadIdx.x, blk = blockIdx.x;
  float m = 1.0f / (1.0f + __expf(-caw[0]));
  if (blk < 96) {
    int nlp = (blk < 48) ? blk : blk - 48;
    const float4* pr = (const float4*)(prims + nlp * BD);
    const float4* wr = (const float4*)(ipw + (size_t)((blk < 48 ? 256 : 512) + t) * BD);
    float s0 = 0.f, s1 = 0.f, s2 = 0.f, s3 = 0.f;
#pragma unroll 8
    for (int i = 0; i < 64; ++i) {
      float4 p = pr[i], wv = wr[i];
      s0 = fmaf(p.x, wv.x, s0); s1 = fmaf(p.y, wv.y, s1);
      s2 = fmaf(p.z, wv.z, s2); s3 = fmaf(p.w, wv.w, s3);
    }
    ws[(blk < 48 ? WS_KP : WS_VP) + nlp * BD + t] = (s0 + s1) + (s2 + s3);
  } else if (blk < 144) {
    int nlp = blk - 96, n = nlp >> 4;
    const float* pr = prims + nlp * BD;
    const float* wqn = wq + (size_t)n * BD * BD + t;
    float s0 = 0.f, s1 = 0.f, s2 = 0.f, s3 = 0.f;
#pragma unroll 4
    for (int o = 0; o < BD; o += 4) {
      s0 = fmaf(pr[o + 0], wqn[(size_t)(o + 0) * BD], s0);
      s1 = fmaf(pr[o + 1], wqn[(size_t)(o + 1) * BD], s1);
      s2 = fmaf(pr[o + 2], wqn[(size_t)(o + 2) * BD], s2);
      s3 = fmaf(pr[o + 3], wqn[(size_t)(o + 3) * BD], s3);
    }
    ws[WS_PQ + nlp * BD + t] = ((s0 + s1) + (s2 + s3)) * (1.0f / 16.0f);
  } else {
    const float4* bv = (const float4*)(ipb + 512);
    const float4* orow = (const float4*)(outw + (size_t)t * BD);
    float s0 = 0.f, s1 = 0.f, s2 = 0.f, s3 = 0.f;
#pragma unroll 8
    for (int i = 0; i < 64; ++i) {
      float4 p = bv[i], wv = orow[i];
      s0 = fmaf(p.x, wv.x, s0); s1 = fmaf(p.y, wv.y, s1);
      s2 = fmaf(p.z, wv.z, s2); s3 = fmaf(p.w, wv.w, s3);
    }
    ws[WS_OB + t] = m * (((s0 + s1) + (s2 + s3)) + outb[t]);
    if (t == 0) {
      for (int n = 0; n < 3; ++n) {
        float a = lvlw[n * 2], b = lvlw[n * 2 + 1];
        float mx = fmaxf(a, b);
        float ea = __expf(a - mx), eb = __expf(b - mx);
        float inv = 1.0f / (ea + eb);
        ws[WS_LW + n * 2] = ea * inv;
        ws[WS_LW + n * 2 + 1] = eb * inv;
      }
      ws[WS_LW + 6] = 0.f; ws[WS_LW + 7] = 0.f;
    }
  }
}

// ---------------- pre2: fragment pack (unchanged from r5, proven) ----------------
__global__ void hpm_pre2(const float* __restrict__ prims, const float* __restrict__ wg,
                         const float* __restrict__ ipw, const float* __restrict__ ipb,
                         const float* __restrict__ outw, const float* __restrict__ caw,
                         float* __restrict__ ws) {
  int t = threadIdx.x, blk = blockIdx.x;
  float m = 1.0f / (1.0f + __expf(-caw[0]));
  unsigned short* WZ = (unsigned short*)(ws + WS_WZF);
  unsigned short* MF = (unsigned short*)(ws + WS_MF);
  if (blk < 192) {
    int h = blk / 48, nlp = blk % 48;
    const float* kpr = ws + WS_KP + nlp * BD + h * 64;
    const float* ip = ipw + (size_t)(h * 64) * BD + t;
    float s0 = 0.f, s1 = 0.f, s2 = 0.f, s3 = 0.f;
#pragma unroll 4
    for (int o = 0; o < 64; o += 4) {
      s0 = fmaf(ip[(size_t)(o + 0) * BD], kpr[o + 0], s0);
      s1 = fmaf(ip[(size_t)(o + 1) * BD], kpr[o + 1], s1);
      s2 = fmaf(ip[(size_t)(o + 2) * BD], kpr[o + 2], s2);
      s3 = fmaf(ip[(size_t)(o + 3) * BD], kpr[o + 3], s3);
    }
    WZ[frag_idx(t, 51 + h * 49 + nlp)] = f2bf(((s0 + s1) + (s2 + s3)) * 0.125f);
  } else if (blk < 196) {
    int h = blk - 192;
    const float* bk = ipb + 256 + h * 64;
    const float* ip = ipw + (size_t)(h * 64) * BD + t;
    float s = 0.f;
#pragma unroll 4
    for (int o = 0; o < 64; ++o) s = fmaf(ip[(size_t)o * BD], bk[o], s);
    WZ[frag_idx(t, 51 + h * 49 + 48)] = f2bf(s * 0.125f);
  } else if (blk < 388) {
    int q = blk - 196;
    int h = q / 48, nlp = q % 48;
    const float4* vp = (const float4*)(ws + WS_VP + nlp * BD + h * 64);
    const float4* orow = (const float4*)(outw + (size_t)t * BD + h * 64);
    float s0 = 0.f, s1 = 0.f, s2 = 0.f, s3 = 0.f;
#pragma unroll 8
    for (int i = 0; i < 16; ++i) {
      float4 p = vp[i], wv = orow[i];
      s0 = fmaf(p.x, wv.x, s0); s1 = fmaf(p.y, wv.y, s1);
      s2 = fmaf(p.z, wv.z, s2); s3 = fmaf(p.w, wv.w, s3);
    }
    MF[frag_idx(h * 48 + nlp, t)] = f2bf(m * ((s0 + s1) + (s2 + s3)));
  } else if (blk == 388) {
    if (t < 196) {
      int h = t / 49, j = t % 49;
      const float* bq = ipb + h * 64;
      float s = 0.f;
      if (j < 48) {
        const float* kpr = ws + WS_KP + j * BD + h * 64;
        for (int o = 0; o < 64; ++o) s = fmaf(bq[o], kpr[o], s);
      } else {
        const float* bk = ipb + 256 + h * 64;
        for (int o = 0; o < 64; ++o) s = fmaf(bq[o], bk[o], s);
      }
      ws[WS_BQK + h * 64 + j] = s * 0.125f;
    }
  } else if (blk < 440) {
    int col = blk - 389;
    float v = (col < 3) ? wg[col * BD + t] : ws[WS_PQ + (col - 3) * BD + t];
    WZ[frag_idx(t, col)] = f2bf(v);
  } else if (blk == 440) {
#pragma unroll
    for (int c = 247; c < 256; ++c) WZ[frag_idx(t, c)] = 0;
  } else if (blk < 489) {
    int i = blk - 441;
    MF[frag_idx(192 + i, t)] = f2bf((1.0f - m) * prims[i * BD + t]);
  } else {
    MF[frag_idx(240, t)] = f2bf(ws[WS_OB + t]);
#pragma unroll
    for (int k = 241; k < 256; ++k) MF[frag_idx(k, t)] = 0;
  }
}

// Build G into SB (single 8192-half buffer). LO=0: hi part; LO=1: lo (residual) part.
template<int LO>
__device__ __forceinline__ void build_G(unsigned short* SB, const float* cbuf,
                                        const float* rbuf, const float* abuf, int tid) {
  if (tid < 128) {
    int row = tid >> 2, h = tid & 3;
    int xr = (row & 7) << 3;
    int base = row * 256;
    const float* cb = cbuf + row * 48;
    const float* ab = abuf + (row * 4 + h) * 3;
#pragma unroll
    for (int g = 0; g < 6; ++g) {
      float an = ab[g >> 1];
      unsigned int pk[4];
#pragma unroll
      for (int q2 = 0; q2 < 4; ++q2) {
        float g0 = an * cb[g * 8 + q2 * 2 + 0];
        float g1 = an * cb[g * 8 + q2 * 2 + 1];
        unsigned short v0, v1;
        if (LO) { v0 = f2bf(g0 - bf2f(f2bf(g0))); v1 = f2bf(g1 - bf2f(f2bf(g1))); }
        else    { v0 = f2bf(g0);                  v1 = f2bf(g1); }
        pk[q2] = (unsigned int)v0 | ((unsigned int)v1 << 16);
      }
      int k0 = (h * 48 + g * 8) ^ xr;   // XOR hits bits 3-5 only: stays 8-aligned
      *(uint4*)&SB[base + k0] = make_uint4(pk[0], pk[1], pk[2], pk[3]);
    }
  } else if (tid < 160) {
    int row = tid - 128;
    int xr = (row & 7) << 3;
    int base = row * 256;
    const float* cb = cbuf + row * 48;
    const float* rb = rbuf + row * 4;
#pragma unroll
    for (int g = 0; g < 6; ++g) {
      float rn = rb[g >> 1];
      unsigned int pk[4];
#pragma unroll
      for (int q2 = 0; q2 < 4; ++q2) {
        float g0 = rn * cb[g * 8 + q2 * 2 + 0];
        float g1 = rn * cb[g * 8 + q2 * 2 + 1];
        unsigned short v0, v1;
        if (LO) { v0 = f2bf(g0 - bf2f(f2bf(g0))); v1 = f2bf(g1 - bf2f(f2bf(g1))); }
        else    { v0 = f2bf(g0);                  v1 = f2bf(g1); }
        pk[q2] = (unsigned int)v0 | ((unsigned int)v1 << 16);
      }
      int k0 = (192 + g * 8) ^ xr;
      *(uint4*)&SB[base + k0] = make_uint4(pk[0], pk[1], pk[2], pk[3]);
    }
    int k240 = 240 ^ xr;   // OB row: hi=1.0, lo=0; k 241..255 zero both passes
    *(uint4*)&SB[base + k240] = make_uint4(LO ? 0u : 0x3f80u, 0u, 0u, 0u);
    int k248 = 248 ^ xr;
    *(uint4*)&SB[base + k248] = make_uint4(0u, 0u, 0u, 0u);
  }
}

// ---------------- main: 32 rows/block, slim LDS (5 blocks/CU) ----------------
__global__ __launch_bounds__(256, 5) void hpm_main(
    const float* __restrict__ z, const float* __restrict__ wg,
    const float* __restrict__ bg, const float* __restrict__ lng,
    const float* __restrict__ lnb, const float* __restrict__ ws,
    float* __restrict__ out) {
  // SB reused: phase1 z [32][264]; phase2 T [32][264] (overlay); phase3 G [32][256] (hi then lo)
  __shared__ unsigned short SB[8448];
  __shared__ float cbuf[32 * 48];
  __shared__ float rbuf[32 * 4];
  __shared__ float abuf[32 * 12];
  __shared__ float lred[32 * 8];
  __shared__ float lgb[512];

  const int tid = threadIdx.x;
  const int l = tid & 63;
  const int w = tid >> 6;
  const int l15 = l & 15, l16 = l >> 4;
  const int r0 = blockIdx.x * 32;

  lgb[tid] = lng[tid];
  lgb[256 + tid] = lnb[tid];

  // ---- stage z -> SB bf16 [32][264], fused exact fp32 router ----
  {
    const int srow = tid >> 3, seg = tid & 7;
    const float* zr = z + (size_t)(r0 + srow) * BD + seg * 32;
    float l0 = 0.f, l1 = 0.f, l2 = 0.f;
    unsigned int pk[16];
#pragma unroll
    for (int j = 0; j < 8; ++j) {
      float4 zv = ((const float4*)zr)[j];
      const float* wgp = wg + seg * 32 + j * 4;
      float4 w0 = *(const float4*)(wgp);
      float4 w1 = *(const float4*)(wgp + BD);
      float4 w2 = *(const float4*)(wgp + 2 * BD);
      l0 = fmaf(zv.x, w0.x, fmaf(zv.y, w0.y, fmaf(zv.z, w0.z, fmaf(zv.w, w0.w, l0))));
      l1 = fmaf(zv.x, w1.x, fmaf(zv.y, w1.y, fmaf(zv.z, w1.z, fmaf(zv.w, w1.w, l1))));
      l2 = fmaf(zv.x, w2.x, fmaf(zv.y, w2.y, fmaf(zv.z, w2.z, fmaf(zv.w, w2.w, l2))));
      pk[j * 2 + 0] = (unsigned int)f2bf(zv.x) | ((unsigned int)f2bf(zv.y) << 16);
      pk[j * 2 + 1] = (unsigned int)f2bf(zv.z) | ((unsigned int)f2bf(zv.w) << 16);
    }
    unsigned short* zl = &SB[srow * 264 + seg * 32];
#pragma unroll
    for (int q = 0; q < 4; ++q)
      *(uint4*)(zl + q * 8) = make_uint4(pk[q * 4], pk[q * 4 + 1], pk[q * 4 + 2], pk[q * 4 + 3]);
#pragma unroll
    for (int mk = 1; mk < 8; mk <<= 1) {
      l0 += __shfl_xor(l0, mk, 64);
      l1 += __shfl_xor(l1, mk, 64);
      l2 += __shfl_xor(l2, mk, 64);
    }
    if (seg == 0) {
      l0 += bg[0]; l1 += bg[1]; l2 += bg[2];
      float mx = fmaxf(l0, fmaxf(l1, l2));
      float e0 = __expf(l0 - mx), e1 = __expf(l1 - mx), e2 = __expf(l2 - mx);
      float inv = 1.0f / (e0 + e1 + e2);
      float p0 = e0 * inv, p1 = e1 * inv, p2 = e2 * inv;
      int drop = (p2 <= p1 && p2 <= p0) ? 2 : ((p1 <= p0) ? 1 : 0);
      float a = (drop == 0) ? 0.f : p0;
      float b = (drop == 1) ? 0.f : p1;
      float c = (drop == 2) ? 0.f : p2;
      float den = 1.0f / (a + b + c + 1e-9f);
      rbuf[srow * 4 + 0] = a * den; rbuf[srow * 4 + 1] = b * den; rbuf[srow * 4 + 2] = c * den;
    }
  }
  __syncthreads();

  // ---- GEMM1: T = z @ Wz (barrier-free k-loop) ----
  f32x4 zero4 = {0.f, 0.f, 0.f, 0.f};
  f32x4 acc[2][4];
#pragma unroll
  for (int rt = 0; rt < 2; ++rt)
#pragma unroll
    for (int j = 0; j < 4; ++j) acc[rt][j] = zero4;
  const uint4* wzf = (const uint4*)(ws + WS_WZF);
#pragma unroll
  for (int kt = 0; kt < 8; ++kt) {
    bf16x8 a0 = __builtin_bit_cast(bf16x8, *(const uint4*)&SB[l15 * 264 + kt * 32 + l16 * 8]);
    bf16x8 a1 = __builtin_bit_cast(bf16x8, *(const uint4*)&SB[(16 + l15) * 264 + kt * 32 + l16 * 8]);
#pragma unroll
    for (int j = 0; j < 4; ++j) {
      bf16x8 b = __builtin_bit_cast(bf16x8, wzf[(kt * 16 + (w * 4 + j)) * 64 + l]);
      acc[0][j] = __builtin_amdgcn_mfma_f32_16x16x32_bf16(a0, b, acc[0][j], 0, 0, 0);
      acc[1][j] = __builtin_amdgcn_mfma_f32_16x16x32_bf16(a1, b, acc[1][j], 0, 0, 0);
    }
  }
  __syncthreads();   // all waves done reading z -> safe to overlay T

  // ---- write T (bf16) over z region ----
#pragma unroll
  for (int rt = 0; rt < 2; ++rt)
#pragma unroll
    for (int j = 0; j < 4; ++j)
#pragma unroll
      for (int r = 0; r < 4; ++r) {
        int row = rt * 16 + l16 * 4 + r;
        int col = (w * 4 + j) * 16 + l15;
        SB[row * 264 + col] = f2bf(acc[rt][j][r]);
      }
  __syncthreads();

  // ---- alpha softmax: 192 threads (row, n*2+lv) ----
  if (tid < 192) {
    int row = tid & 31, grp = tid >> 5;
    const unsigned short* tb = &SB[row * 264 + 3 + grp * 8];
    float sc[8]; float mx = -1e30f;
#pragma unroll
    for (int p = 0; p < 8; ++p) { sc[p] = bf2f(tb[p]); mx = fmaxf(mx, sc[p]); }
    float sum = 0.f;
#pragma unroll
    for (int p = 0; p < 8; ++p) { sc[p] = __expf(sc[p] - mx); sum += sc[p]; }
    float lwv = ws[WS_LW + grp] / sum;
#pragma unroll
    for (int p = 0; p < 8; ++p) cbuf[row * 48 + grp * 8 + p] = sc[p] * lwv;
  }
  __syncthreads();

  // ---- E2: attention logits + softmax (128 threads: row, h) ----
  if (tid < 128) {
    int row = tid >> 2, h = tid & 3;
    const float* bq = ws + WS_BQK + h * 64;
    const unsigned short* tb = &SB[row * 264 + 51 + h * 49];
    float atk[3];
#pragma unroll
    for (int n = 0; n < 3; ++n) {
      float s = 0.f;
#pragma unroll
      for (int i = 0; i < 16; ++i)
        s = fmaf(cbuf[row * 48 + n * 16 + i], bf2f(tb[n * 16 + i]) + bq[n * 16 + i], s);
      atk[n] = s;
    }
    float cb = bf2f(tb[48]) + bq[48];
    float a0 = atk[0] + cb, a1 = atk[1] + cb, a2 = atk[2] + cb;
    float mx = fmaxf(a0, fmaxf(a1, a2));
    float e0 = __expf(a0 - mx), e1 = __expf(a1 - mx), e2 = __expf(a2 - mx);
    float inv = 1.0f / (e0 + e1 + e2);
    abuf[(row * 4 + h) * 3 + 0] = e0 * inv;
    abuf[(row * 4 + h) * 3 + 1] = e1 * inv;
    abuf[(row * 4 + h) * 3 + 2] = e2 * inv;
  }
  __syncthreads();

  // ---- GEMM3 in two passes over a single G buffer (hi then lo) ----
  f32x4 acc3[2][4];
#pragma unroll
  for (int rt = 0; rt < 2; ++rt)
#pragma unroll
    for (int j = 0; j < 4; ++j) acc3[rt][j] = zero4;
  const uint4* mf = (const uint4*)(ws + WS_MF);

  build_G<0>(SB, cbuf, rbuf, abuf, tid);   // hi (overwrites T; T dead after E2)
  __syncthreads();
#pragma unroll
  for (int kt = 0; kt < 8; ++kt) {
    uint4 ua[2];
#pragma unroll
    for (int rt = 0; rt < 2; ++rt) {
      int row = rt * 16 + l15;
      ua[rt] = *(const uint4*)&SB[row * 256 + ((kt * 32 + l16 * 8) ^ ((row & 7) << 3))];
    }
#pragma unroll
    for (int j = 0; j < 4; ++j) {
      bf16x8 b = __builtin_bit_cast(bf16x8, mf[(kt * 16 + w * 4 + j) * 64 + l]);
#pragma unroll
      for (int rt = 0; rt < 2; ++rt)
        acc3[rt][j] = __builtin_amdgcn_mfma_f32_16x16x32_bf16(__builtin_bit_cast(bf16x8, ua[rt]), b, acc3[rt][j], 0, 0, 0);
    }
  }
  __syncthreads();
  build_G<1>(SB, cbuf, rbuf, abuf, tid);   // lo residual
  __syncthreads();
#pragma unroll
  for (int kt = 0; kt < 8; ++kt) {
    uint4 ua[2];
#pragma unroll
    for (int rt = 0; rt < 2; ++rt) {
      int row = rt * 16 + l15;
      ua[rt] = *(const uint4*)&SB[row * 256 + ((kt * 32 + l16 * 8) ^ ((row & 7) << 3))];
    }
#pragma unroll
    for (int j = 0; j < 4; ++j) {
      bf16x8 b = __builtin_bit_cast(bf16x8, mf[(kt * 16 + w * 4 + j) * 64 + l]);
#pragma unroll
      for (int rt = 0; rt < 2; ++rt)
        acc3[rt][j] = __builtin_amdgcn_mfma_f32_16x16x32_bf16(__builtin_bit_cast(bf16x8, ua[rt]), b, acc3[rt][j], 0, 0, 0);
    }
  }

  // ---- fused LN ----
  float sm[2][4], sq[2][4];
#pragma unroll
  for (int rt = 0; rt < 2; ++rt)
#pragma unroll
    for (int r = 0; r < 4; ++r) {
      float s = 0.f, q2 = 0.f;
#pragma unroll
      for (int j = 0; j < 4; ++j) { float v = acc3[rt][j][r]; s += v; q2 = fmaf(v, v, q2); }
      sm[rt][r] = s; sq[rt][r] = q2;
    }
#pragma unroll
  for (int mk = 1; mk < 16; mk <<= 1)
#pragma unroll
    for (int rt = 0; rt < 2; ++rt)
#pragma unroll
      for (int r = 0; r < 4; ++r) {
        sm[rt][r] += __shfl_xor(sm[rt][r], mk, 64);
        sq[rt][r] += __shfl_xor(sq[rt][r], mk, 64);
      }
  if (l15 == 0) {
#pragma unroll
    for (int rt = 0; rt < 2; ++rt)
#pragma unroll
      for (int r = 0; r < 4; ++r) {
        int row = rt * 16 + l16 * 4 + r;
        lred[(row * 4 + w) * 2 + 0] = sm[rt][r];
        lred[(row * 4 + w) * 2 + 1] = sq[rt][r];
      }
  }
  __syncthreads();
#pragma unroll
  for (int rt = 0; rt < 2; ++rt)
#pragma unroll
    for (int r = 0; r < 4; ++r) {
      int row = rt * 16 + l16 * 4 + r;
      float ts = lred[(row * 4 + 0) * 2] + lred[(row * 4 + 1) * 2] + lred[(row * 4 + 2) * 2] + lred[(row * 4 + 3) * 2];
      float tq = lred[(row * 4 + 0) * 2 + 1] + lred[(row * 4 + 1) * 2 + 1] + lred[(row * 4 + 2) * 2 + 1] + lred[(row * 4 + 3) * 2 + 1];
      float mu = ts * (1.0f / 256.0f);
      float var = tq * (1.0f / 256.0f) - mu * mu;
      float rstd = rsqrtf(var + 1e-5f);
#pragma unroll
      for (int j = 0; j < 4; ++j) {
        int col = (w * 4 + j) * 16 + l15;
        float v = (acc3[rt][j][r] - mu) * rstd * lgb[col] + lgb[256 + col];
        out[(size_t)(r0 + row) * BD + col] = v;
      }
    }
}

extern "C" void kernel_launch(void* const* d_in, const int* in_sizes, int n_in,
                              void* d_out, int out_size, void* d_ws, size_t ws_size,
                              hipStream_t stream) {
  const float* z     = (const float*)d_in[0];
  const float* prims = (const float*)d_in[1];
  const float* lvlw  = (const float*)d_in[2];
  const float* wq    = (const float*)d_in[3];
  const float* wg    = (const float*)d_in[4];
  const float* bg    = (const float*)d_in[5];
  const float* ipw   = (const float*)d_in[6];
  const float* ipb   = (const float*)d_in[7];
  const float* outw  = (const float*)d_in[8];
  const float* outb  = (const float*)d_in[9];
  const float* lng   = (const float*)d_in[10];
  const float* lnb   = (const float*)d_in[11];
  const float* caw   = (const float*)d_in[12];
  float* wsf = (float*)d_ws;
  float* out = (float*)d_out;

  if (ws_size < (size_t)WS_TOTAL * sizeof(float)) return;  // 412 KB

  const int B = in_sizes[0] / BD;   // 65536
  hpm_pre1<<<145, 256, 0, stream>>>(prims, lvlw, wq, ipw, ipb, outw, outb, caw, wsf);
  hpm_pre2<<<490, 256, 0, stream>>>(prims, wg, ipw, ipb, outw, caw, wsf);
  hpm_main<<<B / 32, 256, 0, stream>>>(z, wg, bg, lng, lnb, wsf, out);
}